// Round 9
// baseline (165.452 us; speedup 1.0000x reference)
//
#include <hip/hip_runtime.h>
#include <hip/hip_fp16.h>

constexpr int N_NODES = 50000;
constexpr int N_EDGES = 400000;
constexpr int F = 128;

constexpr int NBUK  = 512;                       // row>>7 buckets (391 used)
constexpr int EPB   = 1024;                      // edges per hist/scatter block
constexpr int NBLK  = (N_EDGES + EPB - 1) / EPB; // 391
constexpr int NBLKP = 392;                       // padded stride for [bucket][block]

typedef _Float16 f16x8 __attribute__((ext_vector_type(8)));
typedef _Float16 f16x4 __attribute__((ext_vector_type(4)));
typedef _Float16 f16x2 __attribute__((ext_vector_type(2)));
typedef float    f32x4 __attribute__((ext_vector_type(4)));

union v8v2 { f16x8 v8; f16x2 v2[4]; };

// XOR swizzle: flips half-index bits 3..5 by row&7 -> conflict-free frag reads.
__device__ __forceinline__ int swz(int row, int colh) {
    return (row * F + colh) ^ ((row & 7) << 3);
}

// ---------------- Kernel 1: weight fusion (tiny) ----------------
// Wall slots (f16 [128][128], natural [o][d]):
//   0: W_lin[0], 1: Wf[0]=W_att[0]@W_lin[0], 2: W_lin[1], 3: Wf[1]
// ball slots (f32 [128]): 0: b[0], 1: W_att[0]@b[0], 2: b[1], 3: W_att[1]@b[1]
__global__ __launch_bounds__(256) void gat_fuse(
    const float* __restrict__ W_lin, const float* __restrict__ b_lin,
    const float* __restrict__ W_att,
    _Float16* __restrict__ Wall, float* __restrict__ ball)
{
    __shared__ float wl[128][8];
    const int h  = blockIdx.x >> 4;
    const int cb = blockIdx.x & 15;
    const int t  = threadIdx.x;
    const float* WL = W_lin + h * F * F;
    const float* WA = W_att + h * F * F;

    {   int p = t >> 1, d0 = (t & 1) * 4;
        float4 v = *(const float4*)(WL + p * F + cb * 8 + d0);
        wl[p][d0+0]=v.x; wl[p][d0+1]=v.y; wl[p][d0+2]=v.z; wl[p][d0+3]=v.w;
    }
    __syncthreads();

    {   int o = t >> 1, j2 = (t & 1) * 4;
        float a0=0, a1=0, a2=0, a3=0;
        const float* war = WA + o * F;
        #pragma unroll 4
        for (int p = 0; p < F; ++p) {
            float wa = war[p];
            a0 += wa * wl[p][j2+0]; a1 += wa * wl[p][j2+1];
            a2 += wa * wl[p][j2+2]; a3 += wa * wl[p][j2+3];
        }
        f16x4 hv; hv[0]=(_Float16)a0; hv[1]=(_Float16)a1;
        hv[2]=(_Float16)a2; hv[3]=(_Float16)a3;
        *(f16x4*)(Wall + (2*h+1) * F * F + o * F + cb * 8 + j2) = hv;
    }

    {   int idx = cb * 1024 + t * 4;
        float4 v = *(const float4*)(WL + idx);
        f16x4 hv; hv[0]=(_Float16)v.x; hv[1]=(_Float16)v.y;
        hv[2]=(_Float16)v.z; hv[3]=(_Float16)v.w;
        *(f16x4*)(Wall + 2*h * F * F + idx) = hv;
    }

    if (cb == 0 && t < F) {
        ball[2*h * F + t] = b_lin[h * F + t];
        float acc = 0;
        const float* war = WA + t * F;
        for (int p = 0; p < F; ++p) acc += war[p] * b_lin[h * F + p];
        ball[(2*h+1) * F + t] = acc;
    }
}

// ---------------- Deterministic counting sort by row>>7 -------------------
// K1: per-block LDS histogram -> bcnt[bucket][block]  (transposed layout)
__global__ __launch_bounds__(256) void gat_hist(
    const int* __restrict__ ei, unsigned* __restrict__ bcnt)
{
    __shared__ unsigned h[NBUK];
    const int t = threadIdx.x, b = blockIdx.x;
    h[t] = 0; h[t + 256] = 0;
    __syncthreads();
    const int base = b * EPB;
    #pragma unroll
    for (int i = 0; i < EPB / 256; ++i) {
        int e = base + i * 256 + t;
        if (e < N_EDGES) atomicAdd(&h[(unsigned)ei[e] >> 7], 1u);
    }
    __syncthreads();
    bcnt[t * NBLKP + b]         = h[t];
    bcnt[(t + 256) * NBLKP + b] = h[t + 256];
}

// K2: one block. Per-bucket totals over contiguous rows -> LDS exclusive scan
// across buckets -> per-(block,bucket) absolute bases bof[bucket][block].
__global__ __launch_bounds__(NBUK) void gat_scan(
    const unsigned* __restrict__ bcnt, unsigned* __restrict__ bof)
{
    __shared__ unsigned s[NBUK];
    const int B = threadIdx.x;                  // bucket id
    unsigned tot = 0;
    for (int b = 0; b < NBLK; ++b) tot += bcnt[B * NBLKP + b];
    s[B] = tot;
    __syncthreads();
    #pragma unroll
    for (int d = 1; d < NBUK; d <<= 1) {
        unsigned u = (B >= d) ? s[B - d] : 0u;
        __syncthreads();
        s[B] += u;
        __syncthreads();
    }
    unsigned run = s[B] - tot;                  // exclusive bucket base
    for (int b = 0; b < NBLK; ++b) {
        unsigned cb = bcnt[B * NBLKP + b];
        bof[B * NBLKP + b] = run;
        run += cb;
    }
}

// K3: scatter with LDS-atomic ranks only (deterministic output: payload
// travels with position; edge kernel writes out[e] by payload).
__global__ __launch_bounds__(256) void gat_scatter(
    const int* __restrict__ ei, const unsigned* __restrict__ bof,
    uint2* __restrict__ sorted)
{
    __shared__ unsigned base[NBUK];
    const int t = threadIdx.x, b = blockIdx.x;
    base[t]       = bof[t * NBLKP + b];
    base[t + 256] = bof[(t + 256) * NBLKP + b];
    __syncthreads();
    const int bs = b * EPB;
    #pragma unroll
    for (int i = 0; i < EPB / 256; ++i) {
        int e = bs + i * 256 + t;
        if (e < N_EDGES) {
            unsigned r = (unsigned)ei[e], c = (unsigned)ei[N_EDGES + e];
            unsigned pos = atomicAdd(&base[r >> 7], 1u);
            sorted[pos] = make_uint2(r | (c << 16), (unsigned)e);
        }
    }
}

// ---------------- Kernel 2: GEMM, 64 nodes/block (782 blocks, ~3/CU) ------
// 16 nodes/wave; 4 weight slots serial with next-slot reg prefetch; outputs
// staged per-wave in LDS -> full-line coalesced global stores.
__global__ __launch_bounds__(256) void gat_gemm(
    const float* __restrict__ x,        // [N][128]
    const _Float16* __restrict__ Wall,  // [4][128][128]
    const float* __restrict__ ball,     // [4][128]
    _Float16* __restrict__ HX,          // [N][2][128]
    _Float16* __restrict__ A2)          // [N][2][128]
{
    __shared__ _Float16 wbuf[F * F];       // 32 KB
    __shared__ _Float16 stag[4][16 * F];   // 16 KB (per-wave 4 KB)

    const int t    = threadIdx.x;
    const int wave = t >> 6;
    const int lane = t & 63;
    const int r16  = lane & 15;
    const int kgrp = lane >> 4;
    const int node_base = blockIdx.x * 64 + wave * 16;

    // x frags: 16 nodes/wave, f32 -> f16, persistent across slots
    f16x8 xf[4];
    {
        int xrow = node_base + r16;
        if (xrow >= N_NODES) xrow = N_NODES - 1;
        const float* xp = x + (size_t)xrow * F + kgrp * 8;
        #pragma unroll
        for (int kk = 0; kk < 4; ++kk) {
            float4 v0 = *(const float4*)(xp + kk * 32);
            float4 v1 = *(const float4*)(xp + kk * 32 + 4);
            f16x8 hv;
            hv[0]=(_Float16)v0.x; hv[1]=(_Float16)v0.y;
            hv[2]=(_Float16)v0.z; hv[3]=(_Float16)v0.w;
            hv[4]=(_Float16)v1.x; hv[5]=(_Float16)v1.y;
            hv[6]=(_Float16)v1.z; hv[7]=(_Float16)v1.w;
            xf[kk] = hv;
        }
    }

    // prologue: stage slot 0
    f16x8 pre[8];
    #pragma unroll
    for (int i = 0; i < 8; ++i)
        pre[i] = *(const f16x8*)(Wall + (size_t)(i * 256 + t) * 8);
    #pragma unroll
    for (int i = 0; i < 8; ++i) {
        int idx8 = i * 256 + t;
        *(f16x8*)(wbuf + swz(idx8 >> 4, (idx8 & 15) * 8)) = pre[i];
    }
    __syncthreads();

    #pragma unroll
    for (int slot = 0; slot < 4; ++slot) {
        if (slot < 3) {     // T14: issue next slot's global loads pre-compute
            const _Float16* Wn = Wall + (slot + 1) * F * F;
            #pragma unroll
            for (int i = 0; i < 8; ++i)
                pre[i] = *(const f16x8*)(Wn + (size_t)(i * 256 + t) * 8);
        }

        _Float16* dstbase = ((slot & 1) ? A2 : HX) + (slot >> 1) * F;

        #pragma unroll
        for (int c = 0; c < 8; ++c) {
            f16x8 aw[4];
            #pragma unroll
            for (int kk = 0; kk < 4; ++kk)
                aw[kk] = *(const f16x8*)(wbuf + swz(c * 16 + r16, kk * 32 + kgrp * 8));
            f32x4 acc = {0.f, 0.f, 0.f, 0.f};
            #pragma unroll
            for (int kk = 0; kk < 4; ++kk)
                acc = __builtin_amdgcn_mfma_f32_16x16x32_f16(aw[kk], xf[kk], acc, 0, 0, 0);
            float4 bv = *(const float4*)(ball + slot * F + c * 16 + kgrp * 4);
            f16x4 hv;
            hv[0] = (_Float16)(acc[0] + bv.x);
            hv[1] = (_Float16)(acc[1] + bv.y);
            hv[2] = (_Float16)(acc[2] + bv.z);
            hv[3] = (_Float16)(acc[3] + bv.w);
            *(f16x4*)(&stag[wave][swz(r16, c * 16 + kgrp * 4)]) = hv;
        }
        {   // readback: full-line coalesced stores (16 nodes x 64B per instr)
            int nd = lane >> 2;
            int node = node_base + nd;
            #pragma unroll
            for (int i = 0; i < 4; ++i) {
                int f0 = (lane & 3) * 8 + i * 32;
                f16x8 v = *(const f16x8*)(&stag[wave][swz(nd, f0)]);
                if (node < N_NODES)
                    *(f16x8*)(dstbase + (size_t)node * 256 + f0) = v;
            }
        }
        __syncthreads();                 // all waves done reading wbuf
        if (slot < 3) {
            #pragma unroll
            for (int i = 0; i < 8; ++i) {
                int idx8 = i * 256 + t;
                *(f16x8*)(wbuf + swz(idx8 >> 4, (idx8 & 15) * 8)) = pre[i];
            }
            __syncthreads();
        }
    }
}

// ---------------- Kernel 3: edge scores on sorted list --------------------
// 8 edges/wave, 8 lanes/edge, 64B/lane/side; XCD-chunked bijective swizzle
// so each XCD walks a contiguous (row-sorted) edge range.
__global__ __launch_bounds__(256) void gat_edge(
    const uint2* __restrict__ sorted,    // packed {r|c<<16, e}
    const _Float16* __restrict__ HX,
    const _Float16* __restrict__ A2,
    float* __restrict__ out)
{
    const int nwg = gridDim.x;
    int bid = blockIdx.x;
    int xcd = bid & 7, loc = bid >> 3;
    int q = nwg >> 3, rr = nwg & 7;
    int wg = (xcd < rr ? xcd * (q + 1) : rr * (q + 1) + (xcd - rr) * q) + loc;

    int lane = threadIdx.x & 63;
    int idx  = wg * 32 + (threadIdx.x >> 6) * 8 + (lane >> 3);
    int hl   = lane & 7;
    if (idx >= N_EDGES) return;

    uint2 rc = sorted[idx];
    int r = rc.x & 0xFFFF;
    int c = rc.x >> 16;

    const _Float16* hp = HX + (size_t)r * 256 + hl * 32;
    const _Float16* ap = A2 + (size_t)c * 256 + hl * 32;
    v8v2 a[4], b[4];
    #pragma unroll
    for (int i = 0; i < 4; ++i) a[i].v8 = *(const f16x8*)(hp + i * 8);
    #pragma unroll
    for (int i = 0; i < 4; ++i) b[i].v8 = *(const f16x8*)(ap + i * 8);

    float p = 0.f;
    #pragma unroll
    for (int i = 0; i < 4; ++i)
        #pragma unroll
        for (int j = 0; j < 4; ++j)
            p = __builtin_amdgcn_fdot2(a[i].v2[j], b[i].v2[j], p, false);

    #pragma unroll
    for (int m = 1; m <= 4; m <<= 1) p += __shfl_xor(p, m);

    if (hl == 0) out[rc.y] = 1.f / (1.f + __expf(-0.5f * p));
}

extern "C" void kernel_launch(void* const* d_in, const int* in_sizes, int n_in,
                              void* d_out, int out_size, void* d_ws, size_t ws_size,
                              hipStream_t stream) {
    const float* x     = (const float*)d_in[0];
    const int*   ei    = (const int*)d_in[1];
    const float* W_lin = (const float*)d_in[2];
    const float* b_lin = (const float*)d_in[3];
    const float* W_att = (const float*)d_in[4];
    float* out = (float*)d_out;

    // ws layout: Wall | ball | HX | A2 | bcnt | bof | sorted  (~57 MB)
    _Float16* Wall = (_Float16*)d_ws;                          // 128 KB
    float*    ball = (float*)(Wall + 4 * F * F);               // 2 KB
    _Float16* HX   = (_Float16*)(ball + 4 * F);                // 25.6 MB
    _Float16* A2   = HX + (size_t)N_NODES * 256;               // 25.6 MB
    unsigned* bcnt = (unsigned*)(A2 + (size_t)N_NODES * 256);  // 800 KB
    unsigned* bof  = bcnt + NBUK * NBLKP;                      // 800 KB
    uint2*    sorted = (uint2*)(bof + NBUK * NBLKP);           // 3.2 MB

    gat_hist<<<NBLK, 256, 0, stream>>>(ei, bcnt);
    gat_scan<<<1, NBUK, 0, stream>>>(bcnt, bof);
    gat_scatter<<<NBLK, 256, 0, stream>>>(ei, bof, sorted);

    gat_fuse<<<32, 256, 0, stream>>>(W_lin, b_lin, W_att, Wall, ball);
    gat_gemm<<<(N_NODES + 63) / 64, 256, 0, stream>>>(x, Wall, ball, HX, A2);

    gat_edge<<<N_EDGES / 32, 256, 0, stream>>>(sorted, HX, A2, out);
}

// Round 10
// 92.439 us; speedup vs baseline: 1.7899x; 1.7899x over previous
//
#include <hip/hip_runtime.h>
#include <hip/hip_fp16.h>

constexpr int N_NODES = 50000;
constexpr int N_EDGES = 400000;
constexpr int F = 128;

constexpr int NBUK  = 512;                       // row>>7 buckets (391 used)
constexpr int EPB   = 1024;                      // edges per hist/scatter block
constexpr int NBLK  = (N_EDGES + EPB - 1) / EPB; // 391
constexpr int NBLKP = 392;                       // padded stride [bucket][block]

typedef _Float16 f16x8 __attribute__((ext_vector_type(8)));
typedef _Float16 f16x4 __attribute__((ext_vector_type(4)));
typedef _Float16 f16x2 __attribute__((ext_vector_type(2)));
typedef float    f32x4 __attribute__((ext_vector_type(4)));

union v8v2 { f16x8 v8; f16x2 v2[4]; };

// XOR swizzle: flips half-index bits 3..5 by row&7 -> conflict-free frag reads.
__device__ __forceinline__ int swz(int row, int colh) {
    return (row * F + colh) ^ ((row & 7) << 3);
}

// ---------------- Kernel 1: weight fusion (tiny) ----------------
// Wall slots (f16 [128][128], natural [o][d]):
//   0: W_lin[0], 1: Wf[0]=W_att[0]@W_lin[0], 2: W_lin[1], 3: Wf[1]
// ball slots (f32 [128]): 0: b[0], 1: W_att[0]@b[0], 2: b[1], 3: W_att[1]@b[1]
__global__ __launch_bounds__(256) void gat_fuse(
    const float* __restrict__ W_lin, const float* __restrict__ b_lin,
    const float* __restrict__ W_att,
    _Float16* __restrict__ Wall, float* __restrict__ ball)
{
    __shared__ float wl[128][8];
    const int h  = blockIdx.x >> 4;
    const int cb = blockIdx.x & 15;
    const int t  = threadIdx.x;
    const float* WL = W_lin + h * F * F;
    const float* WA = W_att + h * F * F;

    {   int p = t >> 1, d0 = (t & 1) * 4;
        float4 v = *(const float4*)(WL + p * F + cb * 8 + d0);
        wl[p][d0+0]=v.x; wl[p][d0+1]=v.y; wl[p][d0+2]=v.z; wl[p][d0+3]=v.w;
    }
    __syncthreads();

    {   int o = t >> 1, j2 = (t & 1) * 4;
        float a0=0, a1=0, a2=0, a3=0;
        const float* war = WA + o * F;
        #pragma unroll 4
        for (int p = 0; p < F; ++p) {
            float wa = war[p];
            a0 += wa * wl[p][j2+0]; a1 += wa * wl[p][j2+1];
            a2 += wa * wl[p][j2+2]; a3 += wa * wl[p][j2+3];
        }
        f16x4 hv; hv[0]=(_Float16)a0; hv[1]=(_Float16)a1;
        hv[2]=(_Float16)a2; hv[3]=(_Float16)a3;
        *(f16x4*)(Wall + (2*h+1) * F * F + o * F + cb * 8 + j2) = hv;
    }

    {   int idx = cb * 1024 + t * 4;
        float4 v = *(const float4*)(WL + idx);
        f16x4 hv; hv[0]=(_Float16)v.x; hv[1]=(_Float16)v.y;
        hv[2]=(_Float16)v.z; hv[3]=(_Float16)v.w;
        *(f16x4*)(Wall + 2*h * F * F + idx) = hv;
    }

    if (cb == 0 && t < F) {
        ball[2*h * F + t] = b_lin[h * F + t];
        float acc = 0;
        const float* war = WA + t * F;
        for (int p = 0; p < F; ++p) acc += war[p] * b_lin[h * F + p];
        ball[(2*h+1) * F + t] = acc;
    }
}

// ---------------- Deterministic counting sort by row>>7 -------------------
// K1: per-block LDS histogram -> bcnt[bucket][block]  (transposed layout)
__global__ __launch_bounds__(256) void gat_hist(
    const int* __restrict__ ei, unsigned* __restrict__ bcnt)
{
    __shared__ unsigned h[NBUK];
    const int t = threadIdx.x, b = blockIdx.x;
    h[t] = 0; h[t + 256] = 0;
    __syncthreads();
    const int base = b * EPB;
    #pragma unroll
    for (int i = 0; i < EPB / 256; ++i) {
        int e = base + i * 256 + t;
        if (e < N_EDGES) atomicAdd(&h[(unsigned)ei[e] >> 7], 1u);
    }
    __syncthreads();
    bcnt[t * NBLKP + b]         = h[t];
    bcnt[(t + 256) * NBLKP + b] = h[t + 256];
}

// K2a: one block PER BUCKET: scan the bucket's row (contiguous) -> row-local
// exclusive prefix bof[B][b], plus bucket total btot[B]. Fully parallel.
__global__ __launch_bounds__(512) void gat_scan_row(
    const unsigned* __restrict__ bcnt, unsigned* __restrict__ bof,
    unsigned* __restrict__ btot)
{
    __shared__ unsigned s[512];
    const int B = blockIdx.x, t = threadIdx.x;
    unsigned v = (t < NBLK) ? bcnt[B * NBLKP + t] : 0u;
    s[t] = v;
    __syncthreads();
    #pragma unroll
    for (int d = 1; d < 512; d <<= 1) {
        unsigned u = (t >= d) ? s[t - d] : 0u;
        __syncthreads();
        s[t] += u;
        __syncthreads();
    }
    if (t < NBLK) bof[B * NBLKP + t] = s[t] - v;   // exclusive within row
    if (t == 511) btot[B] = s[511];
}

// K2b: one block: exclusive scan of 512 bucket totals -> bktBase.
__global__ __launch_bounds__(512) void gat_scan_bkt(
    const unsigned* __restrict__ btot, unsigned* __restrict__ bbase)
{
    __shared__ unsigned s[NBUK];
    const int t = threadIdx.x;
    unsigned v = btot[t];
    s[t] = v;
    __syncthreads();
    #pragma unroll
    for (int d = 1; d < NBUK; d <<= 1) {
        unsigned u = (t >= d) ? s[t - d] : 0u;
        __syncthreads();
        s[t] += u;
        __syncthreads();
    }
    bbase[t] = s[t] - v;
}

// K3: scatter with LDS-atomic ranks only; base = bktBase + row-local prefix.
__global__ __launch_bounds__(256) void gat_scatter(
    const int* __restrict__ ei, const unsigned* __restrict__ bof,
    const unsigned* __restrict__ bbase, uint2* __restrict__ sorted)
{
    __shared__ unsigned base[NBUK];
    const int t = threadIdx.x, b = blockIdx.x;
    base[t]       = bof[t * NBLKP + b] + bbase[t];
    base[t + 256] = bof[(t + 256) * NBLKP + b] + bbase[t + 256];
    __syncthreads();
    const int bs = b * EPB;
    #pragma unroll
    for (int i = 0; i < EPB / 256; ++i) {
        int e = bs + i * 256 + t;
        if (e < N_EDGES) {
            unsigned r = (unsigned)ei[e], c = (unsigned)ei[N_EDGES + e];
            unsigned pos = atomicAdd(&base[r >> 7], 1u);
            sorted[pos] = make_uint2(r | (c << 16), (unsigned)e);
        }
    }
}

// ---------------- Kernel 2: GEMM, 64 nodes/block (782 blocks, ~3/CU) ------
// 16 nodes/wave; 4 weight slots serial with next-slot reg prefetch; outputs
// staged per-wave in LDS -> full-line coalesced global stores.
__global__ __launch_bounds__(256) void gat_gemm(
    const float* __restrict__ x,        // [N][128]
    const _Float16* __restrict__ Wall,  // [4][128][128]
    const float* __restrict__ ball,     // [4][128]
    _Float16* __restrict__ HX,          // [N][2][128]
    _Float16* __restrict__ A2)          // [N][2][128]
{
    __shared__ _Float16 wbuf[F * F];       // 32 KB
    __shared__ _Float16 stag[4][16 * F];   // 16 KB (per-wave 4 KB)

    const int t    = threadIdx.x;
    const int wave = t >> 6;
    const int lane = t & 63;
    const int r16  = lane & 15;
    const int kgrp = lane >> 4;
    const int node_base = blockIdx.x * 64 + wave * 16;

    f16x8 xf[4];
    {
        int xrow = node_base + r16;
        if (xrow >= N_NODES) xrow = N_NODES - 1;
        const float* xp = x + (size_t)xrow * F + kgrp * 8;
        #pragma unroll
        for (int kk = 0; kk < 4; ++kk) {
            float4 v0 = *(const float4*)(xp + kk * 32);
            float4 v1 = *(const float4*)(xp + kk * 32 + 4);
            f16x8 hv;
            hv[0]=(_Float16)v0.x; hv[1]=(_Float16)v0.y;
            hv[2]=(_Float16)v0.z; hv[3]=(_Float16)v0.w;
            hv[4]=(_Float16)v1.x; hv[5]=(_Float16)v1.y;
            hv[6]=(_Float16)v1.z; hv[7]=(_Float16)v1.w;
            xf[kk] = hv;
        }
    }

    f16x8 pre[8];
    #pragma unroll
    for (int i = 0; i < 8; ++i)
        pre[i] = *(const f16x8*)(Wall + (size_t)(i * 256 + t) * 8);
    #pragma unroll
    for (int i = 0; i < 8; ++i) {
        int idx8 = i * 256 + t;
        *(f16x8*)(wbuf + swz(idx8 >> 4, (idx8 & 15) * 8)) = pre[i];
    }
    __syncthreads();

    #pragma unroll
    for (int slot = 0; slot < 4; ++slot) {
        if (slot < 3) {     // T14: issue next slot's global loads pre-compute
            const _Float16* Wn = Wall + (slot + 1) * F * F;
            #pragma unroll
            for (int i = 0; i < 8; ++i)
                pre[i] = *(const f16x8*)(Wn + (size_t)(i * 256 + t) * 8);
        }

        _Float16* dstbase = ((slot & 1) ? A2 : HX) + (slot >> 1) * F;

        #pragma unroll
        for (int c = 0; c < 8; ++c) {
            f16x8 aw[4];
            #pragma unroll
            for (int kk = 0; kk < 4; ++kk)
                aw[kk] = *(const f16x8*)(wbuf + swz(c * 16 + r16, kk * 32 + kgrp * 8));
            f32x4 acc = {0.f, 0.f, 0.f, 0.f};
            #pragma unroll
            for (int kk = 0; kk < 4; ++kk)
                acc = __builtin_amdgcn_mfma_f32_16x16x32_f16(aw[kk], xf[kk], acc, 0, 0, 0);
            float4 bv = *(const float4*)(ball + slot * F + c * 16 + kgrp * 4);
            f16x4 hv;
            hv[0] = (_Float16)(acc[0] + bv.x);
            hv[1] = (_Float16)(acc[1] + bv.y);
            hv[2] = (_Float16)(acc[2] + bv.z);
            hv[3] = (_Float16)(acc[3] + bv.w);
            *(f16x4*)(&stag[wave][swz(r16, c * 16 + kgrp * 4)]) = hv;
        }
        {   // readback: full-line coalesced stores
            int nd = lane >> 2;
            int node = node_base + nd;
            #pragma unroll
            for (int i = 0; i < 4; ++i) {
                int f0 = (lane & 3) * 8 + i * 32;
                f16x8 v = *(const f16x8*)(&stag[wave][swz(nd, f0)]);
                if (node < N_NODES)
                    *(f16x8*)(dstbase + (size_t)node * 256 + f0) = v;
            }
        }
        __syncthreads();
        if (slot < 3) {
            #pragma unroll
            for (int i = 0; i < 8; ++i) {
                int idx8 = i * 256 + t;
                *(f16x8*)(wbuf + swz(idx8 >> 4, (idx8 & 15) * 8)) = pre[i];
            }
            __syncthreads();
        }
    }
}

// ---------------- Kernel 3: edge scores on sorted list --------------------
// 8 edges/wave, 8 lanes/edge, 64B/lane/side; XCD-chunked bijective swizzle
// so each XCD walks a contiguous (row-sorted) edge range.
__global__ __launch_bounds__(256) void gat_edge(
    const uint2* __restrict__ sorted,    // packed {r|c<<16, e}
    const _Float16* __restrict__ HX,
    const _Float16* __restrict__ A2,
    float* __restrict__ out)
{
    const int nwg = gridDim.x;
    int bid = blockIdx.x;
    int xcd = bid & 7, loc = bid >> 3;
    int q = nwg >> 3, rr = nwg & 7;
    int wg = (xcd < rr ? xcd * (q + 1) : rr * (q + 1) + (xcd - rr) * q) + loc;

    int lane = threadIdx.x & 63;
    int idx  = wg * 32 + (threadIdx.x >> 6) * 8 + (lane >> 3);
    int hl   = lane & 7;
    if (idx >= N_EDGES) return;

    uint2 rc = sorted[idx];
    int r = rc.x & 0xFFFF;
    int c = rc.x >> 16;

    const _Float16* hp = HX + (size_t)r * 256 + hl * 32;
    const _Float16* ap = A2 + (size_t)c * 256 + hl * 32;
    v8v2 a[4], b[4];
    #pragma unroll
    for (int i = 0; i < 4; ++i) a[i].v8 = *(const f16x8*)(hp + i * 8);
    #pragma unroll
    for (int i = 0; i < 4; ++i) b[i].v8 = *(const f16x8*)(ap + i * 8);

    float p = 0.f;
    #pragma unroll
    for (int i = 0; i < 4; ++i)
        #pragma unroll
        for (int j = 0; j < 4; ++j)
            p = __builtin_amdgcn_fdot2(a[i].v2[j], b[i].v2[j], p, false);

    #pragma unroll
    for (int m = 1; m <= 4; m <<= 1) p += __shfl_xor(p, m);

    if (hl == 0) out[rc.y] = 1.f / (1.f + __expf(-0.5f * p));
}

extern "C" void kernel_launch(void* const* d_in, const int* in_sizes, int n_in,
                              void* d_out, int out_size, void* d_ws, size_t ws_size,
                              hipStream_t stream) {
    const float* x     = (const float*)d_in[0];
    const int*   ei    = (const int*)d_in[1];
    const float* W_lin = (const float*)d_in[2];
    const float* b_lin = (const float*)d_in[3];
    const float* W_att = (const float*)d_in[4];
    float* out = (float*)d_out;

    // ws layout: Wall | ball | HX | A2 | bcnt | bof | btot | bbase | sorted
    _Float16* Wall = (_Float16*)d_ws;                          // 128 KB
    float*    ball = (float*)(Wall + 4 * F * F);               // 2 KB
    _Float16* HX   = (_Float16*)(ball + 4 * F);                // 25.6 MB
    _Float16* A2   = HX + (size_t)N_NODES * 256;               // 25.6 MB
    unsigned* bcnt = (unsigned*)(A2 + (size_t)N_NODES * 256);  // 800 KB
    unsigned* bof  = bcnt + NBUK * NBLKP;                      // 800 KB
    unsigned* btot = bof + NBUK * NBLKP;                       // 2 KB
    unsigned* bbase= btot + NBUK;                              // 2 KB
    uint2*    sorted = (uint2*)(bbase + NBUK);                 // 3.2 MB

    gat_hist<<<NBLK, 256, 0, stream>>>(ei, bcnt);
    gat_scan_row<<<NBUK, 512, 0, stream>>>(bcnt, bof, btot);
    gat_scan_bkt<<<1, NBUK, 0, stream>>>(btot, bbase);
    gat_scatter<<<NBLK, 256, 0, stream>>>(ei, bof, bbase, sorted);

    gat_fuse<<<32, 256, 0, stream>>>(W_lin, b_lin, W_att, Wall, ball);
    gat_gemm<<<(N_NODES + 63) / 64, 256, 0, stream>>>(x, Wall, ball, HX, A2);

    gat_edge<<<N_EDGES / 32, 256, 0, stream>>>(sorted, HX, A2, out);
}

// Round 11
// 81.365 us; speedup vs baseline: 2.0335x; 1.1361x over previous
//
#include <hip/hip_runtime.h>
#include <hip/hip_fp16.h>

constexpr int N_NODES = 50000;
constexpr int N_EDGES = 400000;
constexpr int F = 128;

constexpr int NBUK  = 512;                       // row>>7 buckets (391 used)
constexpr int EPB   = 1024;                      // edges per hist/scatter block
constexpr int NBLK  = (N_EDGES + EPB - 1) / EPB; // 391
constexpr int NBLKP = 392;                       // padded stride [bucket][block]

typedef _Float16 f16x8 __attribute__((ext_vector_type(8)));
typedef _Float16 f16x4 __attribute__((ext_vector_type(4)));
typedef _Float16 f16x2 __attribute__((ext_vector_type(2)));
typedef float    f32x4 __attribute__((ext_vector_type(4)));

union v8v2 { f16x8 v8; f16x2 v2[4]; };

// XOR swizzle: flips half-index bits 3..5 by row&7 -> conflict-free frag reads.
__device__ __forceinline__ int swz(int row, int colh) {
    return (row * F + colh) ^ ((row & 7) << 3);
}

// =============== Algebra: score(e) = x_r^T M x_c + v.x_r + u.x_c + c0 =====
//   M  = sum_h W_l^T W_a W_l   (128x128)
//   v  = sum_h W_l^T (W_a b),  u = sum_h W_l^T (W_a^T b),  c0 = sum_h b^T W_a b
// fuse1: Wf_h = W_a,h @ W_l,h (f32) ; w1_h = W_a^T b ; w2_h = W_a b
// fuse2: M = sum_h W_l^T Wf_h -> f16 ; u,v,c0 -> uvws

__global__ __launch_bounds__(256) void gat_fuse1(
    const float* __restrict__ W_lin, const float* __restrict__ b_lin,
    const float* __restrict__ W_att,
    float* __restrict__ Wfws, float* __restrict__ w1ws, float* __restrict__ w2ws)
{
    __shared__ float wl[128][8];
    __shared__ float bl[128];
    const int h  = blockIdx.x >> 4;
    const int cb = blockIdx.x & 15;
    const int t  = threadIdx.x;
    const float* WL = W_lin + h * F * F;
    const float* WA = W_att + h * F * F;

    {   int p = t >> 1, d0 = (t & 1) * 4;
        float4 v = *(const float4*)(WL + p * F + cb * 8 + d0);
        wl[p][d0+0]=v.x; wl[p][d0+1]=v.y; wl[p][d0+2]=v.z; wl[p][d0+3]=v.w;
    }
    if (t < 128) bl[t] = b_lin[h * F + t];
    __syncthreads();

    {   // Wf[o][cb*8+j2..+4)
        int o = t >> 1, j2 = (t & 1) * 4;
        float a0=0, a1=0, a2=0, a3=0;
        const float* war = WA + o * F;
        #pragma unroll 4
        for (int p = 0; p < F; ++p) {
            float wa = war[p];
            a0 += wa * wl[p][j2+0]; a1 += wa * wl[p][j2+1];
            a2 += wa * wl[p][j2+2]; a3 += wa * wl[p][j2+3];
        }
        float4 fv = {a0, a1, a2, a3};
        *(float4*)(Wfws + h * F * F + o * F + cb * 8 + j2) = fv;
    }

    if (cb == 0) {
        if (t < 128) {          // w1[p] = sum_o W_a[o][p] * b[o]
            float s = 0;
            #pragma unroll 4
            for (int o = 0; o < F; ++o) s += WA[o * F + t] * bl[o];
            w1ws[h * F + t] = s;
        } else {                // w2[o] = sum_p W_a[o][p] * b[p]
            int o = t - 128;
            float s = 0;
            const float* war = WA + o * F;
            #pragma unroll 4
            for (int p = 0; p < F; ++p) s += war[p] * bl[p];
            w2ws[h * F + o] = s;
        }
    }
}

__global__ __launch_bounds__(256) void gat_fuse2(
    const float* __restrict__ W_lin, const float* __restrict__ b_lin,
    const float* __restrict__ Wfws,
    const float* __restrict__ w1ws, const float* __restrict__ w2ws,
    _Float16* __restrict__ Mall, float* __restrict__ uvws)
{
    __shared__ float wlh[128 * 128];   // 64 KB: W_l,h staged per phase
    __shared__ float wfs[128][8];      // 4 KB:  Wf slice
    __shared__ float red[256];
    const int cb = blockIdx.x;
    const int t  = threadIdx.x;
    const int i  = t >> 1, j2 = (t & 1) * 4;

    float acc0=0, acc1=0, acc2=0, acc3=0;
    float puv = 0;                      // cb==0: t<128 -> u[i]; t>=128 -> v[i]
    const int ii = t & 127;

    for (int h = 0; h < 2; ++h) {
        __syncthreads();
        const float* WL = W_lin + h * F * F;
        #pragma unroll
        for (int q = 0; q < 16; ++q) {
            int idx = (q * 256 + t) * 4;
            *(float4*)(wlh + idx) = *(const float4*)(WL + idx);
        }
        {   int o = t >> 1, jb = (t & 1) * 4;
            float4 v = *(const float4*)(Wfws + h * F * F + o * F + cb * 8 + jb);
            wfs[o][jb+0]=v.x; wfs[o][jb+1]=v.y; wfs[o][jb+2]=v.z; wfs[o][jb+3]=v.w;
        }
        __syncthreads();
        #pragma unroll 4
        for (int o = 0; o < F; ++o) {
            float wv = wlh[o * F + i];
            acc0 += wv * wfs[o][j2+0];
            acc1 += wv * wfs[o][j2+1];
            acc2 += wv * wfs[o][j2+2];
            acc3 += wv * wfs[o][j2+3];
        }
        if (cb == 0) {
            const float* wsrc = (t < 128) ? (w1ws + h * F) : (w2ws + h * F);
            #pragma unroll 4
            for (int o = 0; o < F; ++o) puv += wlh[o * F + ii] * wsrc[o];
        }
    }

    f16x4 hv;
    hv[0]=(_Float16)acc0; hv[1]=(_Float16)acc1;
    hv[2]=(_Float16)acc2; hv[3]=(_Float16)acc3;
    *(f16x4*)(Mall + i * F + cb * 8 + j2) = hv;

    if (cb == 0) {
        uvws[(t < 128 ? 0 : 128) + ii] = puv;     // u[0..127], v[128..255]
        // c0 = sum_h sum_o b[o]*w2[o]  (tree reduce over 256 (h,o) pairs)
        int hh = t >> 7, oo = t & 127;
        red[t] = b_lin[hh * F + oo] * w2ws[hh * F + oo];
        __syncthreads();
        #pragma unroll
        for (int d = 128; d > 0; d >>= 1) {
            if (t < d) red[t] += red[t + d];
            __syncthreads();
        }
        if (t == 0) uvws[256] = red[0];
    }
}

// ---------------- Deterministic counting sort by row>>7 -------------------
__global__ __launch_bounds__(256) void gat_hist(
    const int* __restrict__ ei, unsigned* __restrict__ bcnt)
{
    __shared__ unsigned h[NBUK];
    const int t = threadIdx.x, b = blockIdx.x;
    h[t] = 0; h[t + 256] = 0;
    __syncthreads();
    const int base = b * EPB;
    #pragma unroll
    for (int i = 0; i < EPB / 256; ++i) {
        int e = base + i * 256 + t;
        if (e < N_EDGES) atomicAdd(&h[(unsigned)ei[e] >> 7], 1u);
    }
    __syncthreads();
    bcnt[t * NBLKP + b]         = h[t];
    bcnt[(t + 256) * NBLKP + b] = h[t + 256];
}

__global__ __launch_bounds__(512) void gat_scan_row(
    const unsigned* __restrict__ bcnt, unsigned* __restrict__ bof,
    unsigned* __restrict__ btot)
{
    __shared__ unsigned s[512];
    const int B = blockIdx.x, t = threadIdx.x;
    unsigned v = (t < NBLK) ? bcnt[B * NBLKP + t] : 0u;
    s[t] = v;
    __syncthreads();
    #pragma unroll
    for (int d = 1; d < 512; d <<= 1) {
        unsigned u = (t >= d) ? s[t - d] : 0u;
        __syncthreads();
        s[t] += u;
        __syncthreads();
    }
    if (t < NBLK) bof[B * NBLKP + t] = s[t] - v;
    if (t == 511) btot[B] = s[511];
}

__global__ __launch_bounds__(512) void gat_scan_bkt(
    const unsigned* __restrict__ btot, unsigned* __restrict__ bbase)
{
    __shared__ unsigned s[NBUK];
    const int t = threadIdx.x;
    unsigned v = btot[t];
    s[t] = v;
    __syncthreads();
    #pragma unroll
    for (int d = 1; d < NBUK; d <<= 1) {
        unsigned u = (t >= d) ? s[t - d] : 0u;
        __syncthreads();
        s[t] += u;
        __syncthreads();
    }
    bbase[t] = s[t] - v;
}

__global__ __launch_bounds__(256) void gat_scatter(
    const int* __restrict__ ei, const unsigned* __restrict__ bof,
    const unsigned* __restrict__ bbase, uint2* __restrict__ sorted)
{
    __shared__ unsigned base[NBUK];
    const int t = threadIdx.x, b = blockIdx.x;
    base[t]       = bof[t * NBLKP + b] + bbase[t];
    base[t + 256] = bof[(t + 256) * NBLKP + b] + bbase[t + 256];
    __syncthreads();
    const int bs = b * EPB;
    #pragma unroll
    for (int i = 0; i < EPB / 256; ++i) {
        int e = bs + i * 256 + t;
        if (e < N_EDGES) {
            unsigned r = (unsigned)ei[e], c = (unsigned)ei[N_EDGES + e];
            unsigned pos = atomicAdd(&base[r >> 7], 1u);
            sorted[pos] = make_uint2(r | (c << 16), (unsigned)e);
        }
    }
}

// ---------------- GEMM: Z = x @ M^T (one slot), XH = f16(x), su/sv --------
__global__ __launch_bounds__(256) void gat_gemm(
    const float* __restrict__ x,        // [N][128]
    const _Float16* __restrict__ Mall,  // [128][128] f16
    const float* __restrict__ uvws,     // u[128], v[128], c0
    _Float16* __restrict__ XH, _Float16* __restrict__ Z,
    float* __restrict__ su, float* __restrict__ sv)
{
    __shared__ _Float16 wbuf[F * F];       // 32 KB
    __shared__ _Float16 stag[4][16 * F];   // 16 KB

    const int t    = threadIdx.x;
    const int wave = t >> 6;
    const int lane = t & 63;
    const int r16  = lane & 15;
    const int kgrp = lane >> 4;
    const int node_base = blockIdx.x * 64 + wave * 16;

    // stage M -> LDS swizzled
    #pragma unroll
    for (int i = 0; i < 8; ++i) {
        int idx8 = i * 256 + t;
        *(f16x8*)(wbuf + swz(idx8 >> 4, (idx8 & 15) * 8)) =
            *(const f16x8*)(Mall + (size_t)idx8 * 8);
    }

    // x frags (B-operand)
    f16x8 xf[4];
    {
        int xrow = node_base + r16;
        if (xrow >= N_NODES) xrow = N_NODES - 1;
        const float* xp = x + (size_t)xrow * F + kgrp * 8;
        #pragma unroll
        for (int kk = 0; kk < 4; ++kk) {
            float4 v0 = *(const float4*)(xp + kk * 32);
            float4 v1 = *(const float4*)(xp + kk * 32 + 4);
            f16x8 hv;
            hv[0]=(_Float16)v0.x; hv[1]=(_Float16)v0.y;
            hv[2]=(_Float16)v0.z; hv[3]=(_Float16)v0.w;
            hv[4]=(_Float16)v1.x; hv[5]=(_Float16)v1.y;
            hv[6]=(_Float16)v1.z; hv[7]=(_Float16)v1.w;
            xf[kk] = hv;
        }
    }
    __syncthreads();

    const int node = node_base + r16;

    // Z = M @ x  (D-frag col = node, rows = features)
    #pragma unroll
    for (int c = 0; c < 8; ++c) {
        f16x8 aw[4];
        #pragma unroll
        for (int kk = 0; kk < 4; ++kk)
            aw[kk] = *(const f16x8*)(wbuf + swz(c * 16 + r16, kk * 32 + kgrp * 8));
        f32x4 acc = {0.f, 0.f, 0.f, 0.f};
        #pragma unroll
        for (int kk = 0; kk < 4; ++kk)
            acc = __builtin_amdgcn_mfma_f32_16x16x32_f16(aw[kk], xf[kk], acc, 0, 0, 0);
        f16x4 hv;
        hv[0]=(_Float16)acc[0]; hv[1]=(_Float16)acc[1];
        hv[2]=(_Float16)acc[2]; hv[3]=(_Float16)acc[3];
        *(f16x4*)(&stag[wave][swz(r16, c * 16 + kgrp * 4)]) = hv;
    }
    {   // coalesced Z store
        int nd = lane >> 2;
        int node2 = node_base + nd;
        #pragma unroll
        for (int i = 0; i < 4; ++i) {
            int f0 = (lane & 3) * 8 + i * 32;
            f16x8 v = *(const f16x8*)(&stag[wave][swz(nd, f0)]);
            if (node2 < N_NODES)
                *(f16x8*)(Z + (size_t)node2 * F + f0) = v;
        }
    }
    {   // XH = f16(x), routed through stag for coalescing (wave-local, in-order LDS)
        #pragma unroll
        for (int kk = 0; kk < 4; ++kk)
            *(f16x8*)(&stag[wave][swz(r16, kk * 32 + kgrp * 8)]) = xf[kk];
        int nd = lane >> 2;
        int node2 = node_base + nd;
        #pragma unroll
        for (int i = 0; i < 4; ++i) {
            int f0 = (lane & 3) * 8 + i * 32;
            f16x8 v = *(const f16x8*)(&stag[wave][swz(nd, f0)]);
            if (node2 < N_NODES)
                *(f16x8*)(XH + (size_t)node2 * F + f0) = v;
        }
    }
    {   // su = u.x + c0 ; sv = v.x   (4-lane k-group reduce)
        float pu = 0.f, pv = 0.f;
        #pragma unroll
        for (int kk = 0; kk < 4; ++kk) {
            int kb = kgrp * 8 + kk * 32;
            float4 u0 = *(const float4*)(uvws + kb);
            float4 u1 = *(const float4*)(uvws + kb + 4);
            float4 v0 = *(const float4*)(uvws + 128 + kb);
            float4 v1 = *(const float4*)(uvws + 128 + kb + 4);
            pu += u0.x*(float)xf[kk][0] + u0.y*(float)xf[kk][1]
                + u0.z*(float)xf[kk][2] + u0.w*(float)xf[kk][3]
                + u1.x*(float)xf[kk][4] + u1.y*(float)xf[kk][5]
                + u1.z*(float)xf[kk][6] + u1.w*(float)xf[kk][7];
            pv += v0.x*(float)xf[kk][0] + v0.y*(float)xf[kk][1]
                + v0.z*(float)xf[kk][2] + v0.w*(float)xf[kk][3]
                + v1.x*(float)xf[kk][4] + v1.y*(float)xf[kk][5]
                + v1.z*(float)xf[kk][6] + v1.w*(float)xf[kk][7];
        }
        pu += __shfl_xor(pu, 16); pu += __shfl_xor(pu, 32);
        pv += __shfl_xor(pv, 16); pv += __shfl_xor(pv, 32);
        if (kgrp == 0 && node < N_NODES) {
            su[node] = pu + uvws[256];
            sv[node] = pv;
        }
    }
}

// ---------------- Edge: 16 edges/wave, 4 lanes/edge, sorted + XCD swizzle -
__global__ __launch_bounds__(256) void gat_edge(
    const uint2* __restrict__ sorted,    // packed {r|c<<16, e}
    const _Float16* __restrict__ XH, const _Float16* __restrict__ Z,
    const float* __restrict__ su, const float* __restrict__ sv,
    float* __restrict__ out)
{
    const int nwg = gridDim.x;
    int bid = blockIdx.x;
    int xcd = bid & 7, loc = bid >> 3;
    int q = nwg >> 3, rr = nwg & 7;
    int wg = (xcd < rr ? xcd * (q + 1) : rr * (q + 1) + (xcd - rr) * q) + loc;

    int lane = threadIdx.x & 63;
    int idx  = wg * 64 + (threadIdx.x >> 6) * 16 + (lane >> 2);
    int hl   = lane & 3;
    if (idx >= N_EDGES) return;

    uint2 rc = sorted[idx];
    int r = rc.x & 0xFFFF;
    int c = rc.x >> 16;

    const _Float16* hp = XH + (size_t)r * F + hl * 32;
    const _Float16* ap = Z  + (size_t)c * F + hl * 32;
    v8v2 a[4], b[4];
    #pragma unroll
    for (int i = 0; i < 4; ++i) a[i].v8 = *(const f16x8*)(hp + i * 8);
    #pragma unroll
    for (int i = 0; i < 4; ++i) b[i].v8 = *(const f16x8*)(ap + i * 8);

    float p = 0.f;
    #pragma unroll
    for (int i = 0; i < 4; ++i)
        #pragma unroll
        for (int j = 0; j < 4; ++j)
            p = __builtin_amdgcn_fdot2(a[i].v2[j], b[i].v2[j], p, false);

    p += __shfl_xor(p, 1);
    p += __shfl_xor(p, 2);

    if (hl == 0) {
        float s = p + su[c] + sv[r];
        out[rc.y] = 1.f / (1.f + __expf(-0.5f * s));
    }
}

extern "C" void kernel_launch(void* const* d_in, const int* in_sizes, int n_in,
                              void* d_out, int out_size, void* d_ws, size_t ws_size,
                              hipStream_t stream) {
    const float* x     = (const float*)d_in[0];
    const int*   ei    = (const int*)d_in[1];
    const float* W_lin = (const float*)d_in[2];
    const float* b_lin = (const float*)d_in[3];
    const float* W_att = (const float*)d_in[4];
    float* out = (float*)d_out;

    // ws: Wfws | w1 | w2 | uv | Mall | XH | Z | su | sv | bcnt | bof | btot | bbase | sorted
    float*    Wfws  = (float*)d_ws;                         // 128 KB
    float*    w1ws  = Wfws + 2 * F * F;                     // 1 KB
    float*    w2ws  = w1ws + 2 * F;                         // 1 KB
    float*    uvws  = w2ws + 2 * F;                         // 258 f32 -> pad 512
    _Float16* Mall  = (_Float16*)(uvws + 512);              // 32 KB
    _Float16* XH    = Mall + F * F;                         // 12.8 MB
    _Float16* Z     = XH + (size_t)N_NODES * F;             // 12.8 MB
    float*    su    = (float*)(Z + (size_t)N_NODES * F);    // 200 KB
    float*    sv    = su + N_NODES;                         // 200 KB
    unsigned* bcnt  = (unsigned*)(sv + N_NODES);            // 800 KB
    unsigned* bof   = bcnt + NBUK * NBLKP;                  // 800 KB
    unsigned* btot  = bof + NBUK * NBLKP;                   // 2 KB
    unsigned* bbase = btot + NBUK;                          // 2 KB
    uint2*    sorted= (uint2*)(bbase + NBUK);               // 3.2 MB

    gat_hist<<<NBLK, 256, 0, stream>>>(ei, bcnt);
    gat_scan_row<<<NBUK, 512, 0, stream>>>(bcnt, bof, btot);
    gat_scan_bkt<<<1, NBUK, 0, stream>>>(btot, bbase);
    gat_scatter<<<NBLK, 256, 0, stream>>>(ei, bof, bbase, sorted);

    gat_fuse1<<<32, 256, 0, stream>>>(W_lin, b_lin, W_att, Wfws, w1ws, w2ws);
    gat_fuse2<<<16, 256, 0, stream>>>(W_lin, b_lin, Wfws, w1ws, w2ws, Mall, uvws);
    gat_gemm<<<(N_NODES + 63) / 64, 256, 0, stream>>>(x, Mall, uvws, XH, Z, su, sv);

    gat_edge<<<N_EDGES / 64, 256, 0, stream>>>(sorted, XH, Z, su, sv, out);
}

// Round 12
// 72.042 us; speedup vs baseline: 2.2966x; 1.1294x over previous
//
#include <hip/hip_runtime.h>
#include <hip/hip_fp16.h>

constexpr int N_NODES = 50000;
constexpr int N_EDGES = 400000;
constexpr int F = 128;

typedef _Float16 f16x8 __attribute__((ext_vector_type(8)));
typedef _Float16 f16x4 __attribute__((ext_vector_type(4)));
typedef _Float16 f16x2 __attribute__((ext_vector_type(2)));
typedef float    f32x4 __attribute__((ext_vector_type(4)));

union v8v2 { f16x8 v8; f16x2 v2[4]; };

// XOR swizzle: flips half-index bits 3..5 by row&7 -> conflict-free frag reads.
__device__ __forceinline__ int swz(int row, int colh) {
    return (row * F + colh) ^ ((row & 7) << 3);
}

// =============== Algebra: score(e) = x_r^T M x_c + v.x_r + u.x_c + c0 =====
//   M  = sum_h W_l^T W_a W_l  (f16 [128][128])
//   u  = sum_h W_l^T (W_a^T b)  (col-side),  v = sum_h W_l^T (W_a b) (row-side)
//   c0 = sum_h b^T W_a b
// Single merged kernel, 16 blocks (cb = 8-col slice of M), W_l staged once
// per head serving both the Wf product and the M accumulation.
__global__ __launch_bounds__(256) void gat_fuse(
    const float* __restrict__ W_lin, const float* __restrict__ b_lin,
    const float* __restrict__ W_att,
    _Float16* __restrict__ Mall, float* __restrict__ uvws)
{
    __shared__ float wlh[F * F];     // 64 KB: W_l,h
    __shared__ float wfs[F][8];      // 4 KB:  Wf slice [o][j]
    __shared__ float bl[F];
    __shared__ float w12[2 * F];     // w1 = W_a^T b | w2 = W_a b   (block 0)
    __shared__ float red[256];

    const int cb = blockIdx.x;
    const int t  = threadIdx.x;
    const int i  = t >> 1, j2 = (t & 1) * 4;
    const int ii = t & 127;

    float acc0 = 0, acc1 = 0, acc2 = 0, acc3 = 0;
    float puv = 0;
    float c0s = 0;

    for (int h = 0; h < 2; ++h) {
        __syncthreads();                         // wlh/bl reuse across h
        const float* WL = W_lin + h * F * F;
        const float* WA = W_att + h * F * F;
        #pragma unroll
        for (int q = 0; q < 16; ++q) {
            int idx = (q * 256 + t) * 4;
            *(float4*)(wlh + idx) = *(const float4*)(WL + idx);
        }
        if (t < F) bl[t] = b_lin[h * F + t];
        __syncthreads();

        {   // wfs[o][jb..+4) = sum_p W_a[o][p] * W_l[p][cb*8+jb..]
            int o = t >> 1, jb = (t & 1) * 4;
            float a0=0, a1=0, a2=0, a3=0;
            const float* war = WA + o * F;
            #pragma unroll 4
            for (int p = 0; p < F; ++p) {
                float wa = war[p];
                const float* wr = wlh + p * F + cb * 8 + jb;
                a0 += wa * wr[0]; a1 += wa * wr[1];
                a2 += wa * wr[2]; a3 += wa * wr[3];
            }
            wfs[o][jb+0]=a0; wfs[o][jb+1]=a1; wfs[o][jb+2]=a2; wfs[o][jb+3]=a3;
        }
        if (cb == 0) {
            if (t < F) {         // w1[p] = sum_o W_a[o][p]*b[o]
                float s = 0;
                #pragma unroll 4
                for (int o = 0; o < F; ++o) s += WA[o * F + t] * bl[o];
                w12[t] = s;
            } else {             // w2[o] = sum_p W_a[o][p]*b[p]
                int o = t - F;
                float s = 0;
                const float* war = WA + o * F;
                #pragma unroll 4
                for (int p = 0; p < F; ++p) s += war[p] * bl[p];
                w12[F + o] = s;
            }
        }
        __syncthreads();

        // M acc: acc[j] += sum_o W_l[o][i] * wfs[o][j]
        #pragma unroll 4
        for (int o = 0; o < F; ++o) {
            float wv = wlh[o * F + i];
            acc0 += wv * wfs[o][j2+0];
            acc1 += wv * wfs[o][j2+1];
            acc2 += wv * wfs[o][j2+2];
            acc3 += wv * wfs[o][j2+3];
        }
        if (cb == 0) {
            // u[i] (t<128, from w1) ; v[i] (t>=128, from w2)
            const float* wsrc = (t < F) ? w12 : (w12 + F);
            #pragma unroll 4
            for (int o = 0; o < F; ++o) puv += wlh[o * F + ii] * wsrc[o];
            // c0 partial: sum_o b[o]*w2[o]
            red[t] = (t < F) ? bl[t] * w12[F + t] : 0.f;
            __syncthreads();
            #pragma unroll
            for (int d = 128; d > 0; d >>= 1) {
                if (t < d) red[t] += red[t + d];
                __syncthreads();
            }
            if (t == 0) c0s += red[0];
        }
    }

    f16x4 hv;
    hv[0]=(_Float16)acc0; hv[1]=(_Float16)acc1;
    hv[2]=(_Float16)acc2; hv[3]=(_Float16)acc3;
    *(f16x4*)(Mall + i * F + cb * 8 + j2) = hv;

    if (cb == 0) {
        uvws[(t < F ? 0 : F) + ii] = puv;        // u[0..127], v[128..255]
        if (t == 0) uvws[256] = c0s;
    }
}

// ---------------- GEMM: Z = x @ M^T, XH = f16(x), su/sv epilogue ----------
__global__ __launch_bounds__(256) void gat_gemm(
    const float* __restrict__ x,        // [N][128]
    const _Float16* __restrict__ Mall,  // [128][128] f16
    const float* __restrict__ uvws,     // u[128], v[128], c0
    _Float16* __restrict__ XH, _Float16* __restrict__ Z,
    float* __restrict__ su, float* __restrict__ sv)
{
    __shared__ _Float16 wbuf[F * F];       // 32 KB
    __shared__ _Float16 stag[4][16 * F];   // 16 KB

    const int t    = threadIdx.x;
    const int wave = t >> 6;
    const int lane = t & 63;
    const int r16  = lane & 15;
    const int kgrp = lane >> 4;
    const int node_base = blockIdx.x * 64 + wave * 16;

    // stage M -> LDS swizzled
    #pragma unroll
    for (int i = 0; i < 8; ++i) {
        int idx8 = i * 256 + t;
        *(f16x8*)(wbuf + swz(idx8 >> 4, (idx8 & 15) * 8)) =
            *(const f16x8*)(Mall + (size_t)idx8 * 8);
    }

    // x frags (B-operand)
    f16x8 xf[4];
    {
        int xrow = node_base + r16;
        if (xrow >= N_NODES) xrow = N_NODES - 1;
        const float* xp = x + (size_t)xrow * F + kgrp * 8;
        #pragma unroll
        for (int kk = 0; kk < 4; ++kk) {
            float4 v0 = *(const float4*)(xp + kk * 32);
            float4 v1 = *(const float4*)(xp + kk * 32 + 4);
            f16x8 hv;
            hv[0]=(_Float16)v0.x; hv[1]=(_Float16)v0.y;
            hv[2]=(_Float16)v0.z; hv[3]=(_Float16)v0.w;
            hv[4]=(_Float16)v1.x; hv[5]=(_Float16)v1.y;
            hv[6]=(_Float16)v1.z; hv[7]=(_Float16)v1.w;
            xf[kk] = hv;
        }
    }
    __syncthreads();

    const int node = node_base + r16;

    // Z = M @ x  (D-frag col = node, rows = features)
    #pragma unroll
    for (int c = 0; c < 8; ++c) {
        f16x8 aw[4];
        #pragma unroll
        for (int kk = 0; kk < 4; ++kk)
            aw[kk] = *(const f16x8*)(wbuf + swz(c * 16 + r16, kk * 32 + kgrp * 8));
        f32x4 acc = {0.f, 0.f, 0.f, 0.f};
        #pragma unroll
        for (int kk = 0; kk < 4; ++kk)
            acc = __builtin_amdgcn_mfma_f32_16x16x32_f16(aw[kk], xf[kk], acc, 0, 0, 0);
        f16x4 hv;
        hv[0]=(_Float16)acc[0]; hv[1]=(_Float16)acc[1];
        hv[2]=(_Float16)acc[2]; hv[3]=(_Float16)acc[3];
        *(f16x4*)(&stag[wave][swz(r16, c * 16 + kgrp * 4)]) = hv;
    }
    {   // coalesced Z store
        int nd = lane >> 2;
        int node2 = node_base + nd;
        #pragma unroll
        for (int i = 0; i < 4; ++i) {
            int f0 = (lane & 3) * 8 + i * 32;
            f16x8 v = *(const f16x8*)(&stag[wave][swz(nd, f0)]);
            if (node2 < N_NODES)
                *(f16x8*)(Z + (size_t)node2 * F + f0) = v;
        }
    }
    {   // XH = f16(x) through stag for full-line stores
        #pragma unroll
        for (int kk = 0; kk < 4; ++kk)
            *(f16x8*)(&stag[wave][swz(r16, kk * 32 + kgrp * 8)]) = xf[kk];
        int nd = lane >> 2;
        int node2 = node_base + nd;
        #pragma unroll
        for (int i = 0; i < 4; ++i) {
            int f0 = (lane & 3) * 8 + i * 32;
            f16x8 v = *(const f16x8*)(&stag[wave][swz(nd, f0)]);
            if (node2 < N_NODES)
                *(f16x8*)(XH + (size_t)node2 * F + f0) = v;
        }
    }
    {   // su = u.x + c0 ; sv = v.x   (4-lane k-group reduce)
        float pu = 0.f, pv = 0.f;
        #pragma unroll
        for (int kk = 0; kk < 4; ++kk) {
            int kb = kgrp * 8 + kk * 32;
            float4 u0 = *(const float4*)(uvws + kb);
            float4 u1 = *(const float4*)(uvws + kb + 4);
            float4 v0 = *(const float4*)(uvws + 128 + kb);
            float4 v1 = *(const float4*)(uvws + 128 + kb + 4);
            pu += u0.x*(float)xf[kk][0] + u0.y*(float)xf[kk][1]
                + u0.z*(float)xf[kk][2] + u0.w*(float)xf[kk][3]
                + u1.x*(float)xf[kk][4] + u1.y*(float)xf[kk][5]
                + u1.z*(float)xf[kk][6] + u1.w*(float)xf[kk][7];
            pv += v0.x*(float)xf[kk][0] + v0.y*(float)xf[kk][1]
                + v0.z*(float)xf[kk][2] + v0.w*(float)xf[kk][3]
                + v1.x*(float)xf[kk][4] + v1.y*(float)xf[kk][5]
                + v1.z*(float)xf[kk][6] + v1.w*(float)xf[kk][7];
        }
        pu += __shfl_xor(pu, 16); pu += __shfl_xor(pu, 32);
        pv += __shfl_xor(pv, 16); pv += __shfl_xor(pv, 32);
        if (kgrp == 0 && node < N_NODES) {
            su[node] = pu + uvws[256];
            sv[node] = pv;
        }
    }
}

// ---------------- Edge: unsorted, 16 edges/wave, 4 lanes/edge -------------
// score = dot(XH[r], Z[c]) + su[c] + sv[r]; out = sigmoid(score/2).
__global__ __launch_bounds__(256) void gat_edge(
    const int* __restrict__ ei,          // [2][N_EDGES]
    const _Float16* __restrict__ XH, const _Float16* __restrict__ Z,
    const float* __restrict__ su, const float* __restrict__ sv,
    float* __restrict__ out)
{
    int gid = blockIdx.x * 256 + threadIdx.x;
    int e   = gid >> 2;
    int hl  = threadIdx.x & 3;
    if (e >= N_EDGES) return;

    int r = ei[e];
    int c = ei[N_EDGES + e];

    const _Float16* hp = XH + (size_t)r * F + hl * 32;
    const _Float16* ap = Z  + (size_t)c * F + hl * 32;
    v8v2 a[4], b[4];
    #pragma unroll
    for (int i = 0; i < 4; ++i) a[i].v8 = *(const f16x8*)(hp + i * 8);
    #pragma unroll
    for (int i = 0; i < 4; ++i) b[i].v8 = *(const f16x8*)(ap + i * 8);

    float p = 0.f;
    #pragma unroll
    for (int i = 0; i < 4; ++i)
        #pragma unroll
        for (int j = 0; j < 4; ++j)
            p = __builtin_amdgcn_fdot2(a[i].v2[j], b[i].v2[j], p, false);

    p += __shfl_xor(p, 1);
    p += __shfl_xor(p, 2);

    if (hl == 0) {
        float s = p + su[c] + sv[r];
        out[e] = 1.f / (1.f + __expf(-0.5f * s));
    }
}

extern "C" void kernel_launch(void* const* d_in, const int* in_sizes, int n_in,
                              void* d_out, int out_size, void* d_ws, size_t ws_size,
                              hipStream_t stream) {
    const float* x     = (const float*)d_in[0];
    const int*   ei    = (const int*)d_in[1];
    const float* W_lin = (const float*)d_in[2];
    const float* b_lin = (const float*)d_in[3];
    const float* W_att = (const float*)d_in[4];
    float* out = (float*)d_out;

    // ws: Mall | uvws | XH | Z | su | sv   (~26 MB)
    _Float16* Mall = (_Float16*)d_ws;                       // 32 KB
    float*    uvws = (float*)(Mall + F * F);                // 512 f32
    _Float16* XH   = (_Float16*)(uvws + 512);               // 12.8 MB
    _Float16* Z    = XH + (size_t)N_NODES * F;              // 12.8 MB
    float*    su   = (float*)(Z + (size_t)N_NODES * F);     // 200 KB
    float*    sv   = su + N_NODES;                          // 200 KB

    gat_fuse<<<16, 256, 0, stream>>>(W_lin, b_lin, W_att, Mall, uvws);
    gat_gemm<<<(N_NODES + 63) / 64, 256, 0, stream>>>(x, Mall, uvws, XH, Z, su, sv);
    gat_edge<<<(N_EDGES * 4 + 255) / 256, 256, 0, stream>>>(ei, XH, Z, su, sv, out);
}